// Round 3
// baseline (247.362 us; speedup 1.0000x reference)
//
#include <hip/hip_runtime.h>

#define CH   1024
#define NPTS 80
#define NEG  0.2f
#define INVTEMP 40.0f

typedef __attribute__((ext_vector_type(8))) short short8;
typedef __attribute__((ext_vector_type(4))) float f32x4;

// Split f32 into hi/lo bf16 (RNE). x ~= hi + lo with relative error ~2^-17.
__device__ __forceinline__ void bsplit(float x, short& hs, short& ls) {
  unsigned u = __builtin_bit_cast(unsigned, x);
  unsigned hb = (u + 0x7fffu + ((u >> 16) & 1u)) >> 16;
  float hf = __builtin_bit_cast(float, hb << 16);
  float r = x - hf;
  unsigned u2 = __builtin_bit_cast(unsigned, r);
  hs = (short)hb;
  ls = (short)((u2 + 0x7fffu + ((u2 >> 16) & 1u)) >> 16);
}

__device__ __forceinline__ float leaky(float v) { return v >= 0.f ? v : NEG * v; }

// One block per batch. 512 threads = 8 waves.
// Phase 1: Gram G = X^T X (K=1024) via split-bf16 MFMA, K split over waves.
// Phase 2: adj = G / (norm_n norm_m) -> bf16 hi/lo in LDS (k-padded to 96).
// Phase 3: h = X @ adj (K=80) fused with leaky + w-reduction -> scores s[80].
// Phase 4: softmax(s*40) + 1 -> attn.
// Phase 5: out = x * attn[n].
__launch_bounds__(512, 1)
__global__ void scgcn_fused_kernel(const float* __restrict__ x,
                                   const float* __restrict__ w,
                                   const float* __restrict__ bias,
                                   float* __restrict__ out) {
  __shared__ float G[80][81];
  __shared__ float rn[80];
  __shared__ float ssc[80];
  __shared__ float wl[CH];
  __shared__ __align__(16) short adjh[80][104];   // [m][n(k) padded to 96, stride 104]
  __shared__ __align__(16) short adjl[80][104];
  __shared__ f32x4 attnv[20];

  const int tid  = threadIdx.x;
  const int lane = tid & 63;
  const int wv   = tid >> 6;        // wave 0..7
  const int l15  = lane & 15;
  const int g    = lane >> 4;       // 0..3
  const int b    = blockIdx.x;
  const float* __restrict__ xb = x + (size_t)b * (CH * NPTS);

  // ---- init LDS ----
  for (int i = tid; i < 80 * 81; i += 512) (&G[0][0])[i] = 0.f;
  if (tid < 80) ssc[tid] = 0.f;
  for (int i = tid; i < CH; i += 512) wl[i] = w[i];

  // ---- Phase 1: Gram. Each wave covers 128 channels (4 k-steps of 32). ----
  f32x4 acc[5][5];
  #pragma unroll
  for (int i = 0; i < 5; ++i)
    #pragma unroll
    for (int j = 0; j < 5; ++j) acc[i][j] = (f32x4){0.f, 0.f, 0.f, 0.f};

  for (int ks = 0; ks < 4; ++ks) {
    const int c0 = wv * 128 + ks * 32 + g * 8;
    short8 fh[5], fl[5];
    #pragma unroll
    for (int t = 0; t < 5; ++t) {
      const int n = 16 * t + l15;
      #pragma unroll
      for (int j = 0; j < 8; ++j) {
        short hs, ls2;
        bsplit(xb[(c0 + j) * NPTS + n], hs, ls2);
        fh[t][j] = hs; fl[t][j] = ls2;
      }
    }
    // frag t serves as both A (rows n-tile t) and B (cols m-tile t)
    #pragma unroll
    for (int tn = 0; tn < 5; ++tn)
      #pragma unroll
      for (int tm = 0; tm < 5; ++tm) {
        acc[tn][tm] = __builtin_amdgcn_mfma_f32_16x16x32_bf16(fh[tn], fh[tm], acc[tn][tm], 0, 0, 0);
        acc[tn][tm] = __builtin_amdgcn_mfma_f32_16x16x32_bf16(fh[tn], fl[tm], acc[tn][tm], 0, 0, 0);
        acc[tn][tm] = __builtin_amdgcn_mfma_f32_16x16x32_bf16(fl[tn], fh[tm], acc[tn][tm], 0, 0, 0);
      }
  }
  __syncthreads();   // G zero-init visible to all
  #pragma unroll
  for (int tn = 0; tn < 5; ++tn)
    #pragma unroll
    for (int tm = 0; tm < 5; ++tm)
      #pragma unroll
      for (int r = 0; r < 4; ++r)
        atomicAdd(&G[16 * tn + 4 * g + r][16 * tm + l15], acc[tn][tm][r]);
  __syncthreads();

  // ---- Phase 2: adj -> bf16 hi/lo, transposed-for-B layout [m][n] ----
  if (tid < 80) rn[tid] = 1.0f / fmaxf(sqrtf(G[tid][tid]), 1e-12f);
  __syncthreads();
  for (int i = tid; i < 80 * 104; i += 512) {
    const int m = i / 104;
    const int n = i - m * 104;
    float v = (n < 80) ? G[n][m] * (rn[n] * rn[m]) : 0.f;
    short hs, ls2; bsplit(v, hs, ls2);
    adjh[m][n] = hs; adjl[m][n] = ls2;
  }
  __syncthreads();

  // ---- Phase 3: h = X @ adj, fused leaky + w-reduce. 8 c-tiles per wave. ----
  float sp[5] = {0.f, 0.f, 0.f, 0.f, 0.f};
  for (int chunk = 0; chunk < 2; ++chunk) {
    f32x4 hacc[4][5];
    #pragma unroll
    for (int i = 0; i < 4; ++i)
      #pragma unroll
      for (int j = 0; j < 5; ++j) hacc[i][j] = (f32x4){0.f, 0.f, 0.f, 0.f};

    for (int ksn = 0; ksn < 3; ++ksn) {
      const int nb = 32 * ksn + 8 * g;
      short8 bh[5], bl[5];
      #pragma unroll
      for (int tm = 0; tm < 5; ++tm) {
        bh[tm] = *reinterpret_cast<const short8*>(&adjh[16 * tm + l15][nb]);
        bl[tm] = *reinterpret_cast<const short8*>(&adjl[16 * tm + l15][nb]);
      }
      #pragma unroll
      for (int t4 = 0; t4 < 4; ++t4) {
        const int ct = wv * 8 + chunk * 4 + t4;
        short8 ah, al;
        if (nb < 80) {
          const float* p = xb + (16 * ct + l15) * NPTS + nb;
          f32x4 va = *reinterpret_cast<const f32x4*>(p);
          f32x4 vb = *reinterpret_cast<const f32x4*>(p + 4);
          #pragma unroll
          for (int j = 0; j < 4; ++j) { short hs, ls2; bsplit(va[j], hs, ls2); ah[j] = hs; al[j] = ls2; }
          #pragma unroll
          for (int j = 0; j < 4; ++j) { short hs, ls2; bsplit(vb[j], hs, ls2); ah[4 + j] = hs; al[4 + j] = ls2; }
        } else {
          ah = (short8){0,0,0,0,0,0,0,0};
          al = (short8){0,0,0,0,0,0,0,0};
        }
        #pragma unroll
        for (int tm = 0; tm < 5; ++tm) {
          hacc[t4][tm] = __builtin_amdgcn_mfma_f32_16x16x32_bf16(ah, bh[tm], hacc[t4][tm], 0, 0, 0);
          hacc[t4][tm] = __builtin_amdgcn_mfma_f32_16x16x32_bf16(ah, bl[tm], hacc[t4][tm], 0, 0, 0);
          hacc[t4][tm] = __builtin_amdgcn_mfma_f32_16x16x32_bf16(al, bh[tm], hacc[t4][tm], 0, 0, 0);
        }
      }
    }
    // leaky + w-reduce this chunk's tiles
    #pragma unroll
    for (int t4 = 0; t4 < 4; ++t4) {
      const int cb = 16 * (wv * 8 + chunk * 4 + t4) + 4 * g;
      #pragma unroll
      for (int r = 0; r < 4; ++r) {
        const float wc = wl[cb + r];
        #pragma unroll
        for (int tm = 0; tm < 5; ++tm) sp[tm] += leaky(hacc[t4][tm][r]) * wc;
      }
    }
  }
  #pragma unroll
  for (int tm = 0; tm < 5; ++tm) {
    float v = sp[tm];
    v += __shfl_xor(v, 16);
    v += __shfl_xor(v, 32);
    if (g == 0) atomicAdd(&ssc[16 * tm + l15], v);
  }
  __syncthreads();

  // ---- Phase 4: softmax (wave 0 only) ----
  if (wv == 0) {
    const float b0 = bias[0];
    float v0 = leaky(ssc[lane] + b0) * INVTEMP;
    float v1 = -3.0e38f;
    if (lane < 16) v1 = leaky(ssc[64 + lane] + b0) * INVTEMP;
    float mx = fmaxf(v0, v1);
    #pragma unroll
    for (int off = 32; off >= 1; off >>= 1) mx = fmaxf(mx, __shfl_xor(mx, off));
    float e0 = expf(v0 - mx);
    float e1 = (lane < 16) ? expf(v1 - mx) : 0.f;
    float sum = e0 + e1;
    #pragma unroll
    for (int off = 32; off >= 1; off >>= 1) sum += __shfl_xor(sum, off);
    const float inv = 1.0f / sum;
    ssc[lane] = e0 * inv + 1.0f;
    if (lane < 16) ssc[64 + lane] = e1 * inv + 1.0f;
  }
  __syncthreads();
  if (tid < 20) {
    f32x4 a = { ssc[4 * tid], ssc[4 * tid + 1], ssc[4 * tid + 2], ssc[4 * tid + 3] };
    attnv[tid] = a;
  }
  __syncthreads();

  // ---- Phase 5: out = x * attn[n] ----
  float* __restrict__ ob = out + (size_t)b * (CH * NPTS);
  const f32x4* xv = reinterpret_cast<const f32x4*>(xb);
  f32x4* ov = reinterpret_cast<f32x4*>(ob);
  #pragma unroll 4
  for (int i = tid; i < (CH * NPTS) / 4; i += 512) {
    f32x4 v = xv[i];
    f32x4 a = attnv[i % 20];
    v[0] *= a[0]; v[1] *= a[1]; v[2] *= a[2]; v[3] *= a[3];
    ov[i] = v;
  }
}

extern "C" void kernel_launch(void* const* d_in, const int* in_sizes, int n_in,
                              void* d_out, int out_size, void* d_ws, size_t ws_size,
                              hipStream_t stream) {
  const float* x    = (const float*)d_in[0];
  const float* w    = (const float*)d_in[1];
  const float* bias = (const float*)d_in[2];
  float* out        = (float*)d_out;
  scgcn_fused_kernel<<<256, 512, 0, stream>>>(x, w, bias, out);
}